// Round 10
// baseline (237.160 us; speedup 1.0000x reference)
//
#include <hip/hip_runtime.h>
#include <stdint.h>

// Problem constants: B=2, S=2048, D=1024, H=16, HD=64
#define BB 2
#define SS 2048
#define DD 1024
#define HH 16
#define HD 64
#define BH 32    // B*H
#define BS 4096  // B*S

typedef short bf16x8 __attribute__((ext_vector_type(8)));
typedef float f32x4 __attribute__((ext_vector_type(4)));

static __device__ __forceinline__ unsigned short f2bf(float f) {
    union { float f; unsigned int u; } x;
    x.f = f;
    unsigned int u = x.u;
    unsigned int r = u + 0x7FFFu + ((u >> 16) & 1u);  // round-to-nearest-even
    return (unsigned short)(r >> 16);
}

// async global->LDS, 16B per lane; LDS dst is wave-uniform base + lane*16
static __device__ __forceinline__ void gld16(unsigned short* lds, const unsigned short* g) {
    __builtin_amdgcn_global_load_lds(
        (const __attribute__((address_space(1))) unsigned int*)g,
        (__attribute__((address_space(3))) unsigned int*)lds,
        16, 0, 0);
}

// ---------------------------------------------------------------- fused prep
// blocks [0,4096)     : x f32 -> bf16
// blocks [4096,7168)  : transpose Wqkv -> WqkvT bf16
// blocks [7168,8192)  : transpose Wo   -> WoT   bf16
// (mask-pack lives in qkv_gemm's per-wave tail: its 32MB read overlaps MFMA)
__global__ __launch_bounds__(256) void prep(
    const float* __restrict__ x, unsigned short* __restrict__ xb,
    const float* __restrict__ Wqkv, unsigned short* __restrict__ WqkvT,
    const float* __restrict__ Wo, unsigned short* __restrict__ WoT) {
    __shared__ float tile[32][33];
    int bid = blockIdx.x;
    int tid = threadIdx.x;
    if (bid < 4096) {
        int i = (bid * 256 + tid) * 4;
        float4 v = *(const float4*)(x + i);
        ushort4 o;
        o.x = f2bf(v.x); o.y = f2bf(v.y); o.z = f2bf(v.z); o.w = f2bf(v.w);
        *(ushort4*)(xb + i) = o;
    } else {
        const float* W;
        unsigned short* WT;
        int N, t;
        if (bid < 7168) { W = Wqkv; WT = WqkvT; N = 3072; t = bid - 4096; }
        else            { W = Wo;   WT = WoT;   N = 1024; t = bid - 7168; }
        const int K = 1024;
        int nx = N >> 5;
        int n0 = (t % nx) * 32, k0 = (t / nx) * 32;
        int tx = tid & 31, ty = tid >> 5;  // 32 x 8
#pragma unroll
        for (int i = 0; i < 4; i++)
            tile[ty + i * 8][tx] = W[(size_t)(k0 + ty + i * 8) * N + n0 + tx];
        __syncthreads();
#pragma unroll
        for (int i = 0; i < 4; i++)
            WT[(size_t)(n0 + ty + i * 8) * K + k0 + tx] = f2bf(tile[tx][ty + i * 8]);
    }
}

// ---------------------------------------------------------------- QKV GEMM
// Round-10: BK=64 (was 32). Halves barrier events per block (64 -> 32) --
// the per-K-step fixed cost (2 barriers + vmcnt(0) drain) was the largest
// non-MFMA term of the 2-barrier loop; everything else scales 1:1 per unit K.
// LDS 32KB (A 128x64 + B 128x64), occupancy stays 3 blocks/CU.
// Chunk swizzle generalized mod 8: position p of row r holds chunk
// (p+(r>>1))&7; fragment read pos = ((quad+(l15>>1))&7)*8, k-half 1 at ^32.
// q/k blocks use SWAPPED MFMA operands -> C^T -> ushort4 epilogue.
// Per-wave mask-pack tail overlaps sibling MFMA.
// vB : [BH][32 kt][2 ks2][4 quad][64 hd][8 j] with
// key(ks2,quad,j) = ks2*32 + (j>>2)*16 + quad*4 + (j&3)   (matches attn)
__global__ __launch_bounds__(256) void qkv_gemm(
    const unsigned short* __restrict__ xb,     // [4096][1024]
    const unsigned short* __restrict__ WqkvT,  // [3072][1024]
    const float* __restrict__ bqkv,            // [3072]
    const float* __restrict__ mask,            // [B][S][S]
    unsigned int* __restrict__ mbitsT,         // [B][64 kw][2048 q]
    unsigned short* __restrict__ q_ws,
    unsigned short* __restrict__ k_ws,
    unsigned short* __restrict__ vB) {
    __shared__ unsigned short ldsA[8192], ldsB[8192];  // [128 rows][64 k]
    int gxr = blockIdx.x;
    int tid = threadIdx.x;
    int xcd = gxr & 7, lidx = gxr >> 3;            // lidx in [0,96)
    int m0 = (xcd * 4 + (lidx & 3)) * 128;         // m in [0,32)
    int n0 = (lidx >> 2) * 128;                    // n in [0,24)
    int w = tid >> 6, lane = tid & 63, quad = lane >> 4, l15 = lane & 15;
    int q4 = quad * 4;

    // staging: 32 rows x 8 chunks per gld16 round; 4 rounds cover 128 rows
    int r = tid >> 3, p = tid & 7;
    int c = (p - (r >> 1)) & 7;  // chunk swizzle: LDS pos p of row r holds chunk (p+(r>>1))&7
    const unsigned short* gA = xb + (size_t)(m0 + r) * 1024 + c * 8;
    const unsigned short* gB = WqkvT + (size_t)(n0 + r) * 1024 + c * 8;
    unsigned short* lA = ldsA + w * 512 + lane * 8;   // round i: + i*2048
    unsigned short* lB = ldsB + w * 512 + lane * 8;

    int wm = w >> 1, wn = w & 1;
    int posq = ((quad + (l15 >> 1)) & 7) * 8;
    int aoff = (wm * 64 + l15) * 64 + posq;
    int boff = (wn * 64 + l15) * 64 + posq;

    int t = n0 >> 10;
    f32x4 acc[4][4] = {};
    for (int k0 = 0; k0 < 1024; k0 += 64) {
        __syncthreads();
#pragma unroll
        for (int i = 0; i < 4; i++) {
            gld16(lA + i * 2048, gA + (size_t)i * 32 * 1024 + k0);
            gld16(lB + i * 2048, gB + (size_t)i * 32 * 1024 + k0);
        }
        __syncthreads();
#pragma unroll
        for (int h = 0; h < 2; h++) {
            int ho = h * 32;  // k-half 1: chunk quad+4 = position XOR 4 -> addr XOR 32
            bf16x8 af[4], bfr[4];
#pragma unroll
            for (int i = 0; i < 4; i++) {
                af[i]  = *(const bf16x8*)(ldsA + ((aoff + i * 1024) ^ ho));
                bfr[i] = *(const bf16x8*)(ldsB + ((boff + i * 1024) ^ ho));
            }
            if (t == 2) {
#pragma unroll
                for (int i = 0; i < 4; i++)
#pragma unroll
                    for (int j = 0; j < 4; j++)
                        acc[i][j] = __builtin_amdgcn_mfma_f32_16x16x32_bf16(af[i], bfr[j], acc[i][j], 0, 0, 0);
            } else {
                // swapped operands -> acc holds C^T (rows = hd, cols = s)
#pragma unroll
                for (int i = 0; i < 4; i++)
#pragma unroll
                    for (int j = 0; j < 4; j++)
                        acc[i][j] = __builtin_amdgcn_mfma_f32_16x16x32_bf16(bfr[j], af[i], acc[i][j], 0, 0, 0);
            }
        }
    }

    int ncol0 = n0 + wn * 64;
    int hh = (ncol0 >> 6) & 15;

    if (t == 2) {
        int rowbase = m0 + wm * 64;            // wave-uniform, multiple of 64
        int b = rowbase >> 11;
        int kt = (rowbase >> 6) & 31;
        int bh = b * 16 + hh;
#pragma unroll
        for (int j = 0; j < 4; j++) {
            int hd = j * 16 + l15;
            float bias = bqkv[ncol0 + hd];
#pragma unroll
            for (int i = 0; i < 4; i++) {
                unsigned short* dst = vB +
                    (((((size_t)bh * 32 + kt) * 2 + (i >> 1)) * 4 + quad) * 64 + hd) * 8 + (i & 1) * 4;
                ushort4 pk;
                pk.x = f2bf(acc[i][j][0] + bias);
                pk.y = f2bf(acc[i][j][1] + bias);
                pk.z = f2bf(acc[i][j][2] + bias);
                pk.w = f2bf(acc[i][j][3] + bias);
                *(ushort4*)dst = pk;
            }
        }
    } else {
        // swapped epilogue: thread holds cols n = ncol0 + j*16 + q4 + rr at
        // fixed row s = m0 + wm*64 + i*16 + l15 -> one ushort4 per (i,j)
        unsigned short* dst = (t == 0) ? q_ws : k_ws;
        int sBase = m0 + wm * 64;
#pragma unroll
        for (int j = 0; j < 4; j++) {
            float4 b4 = *(const float4*)(bqkv + ncol0 + j * 16 + q4);
#pragma unroll
            for (int i = 0; i < 4; i++) {
                int row = sBase + i * 16 + l15;
                int b = row >> 11, s = row & 2047;
                int bh = b * 16 + hh;
                ushort4 pk;
                pk.x = f2bf(acc[i][j][0] + b4.x);
                pk.y = f2bf(acc[i][j][1] + b4.y);
                pk.z = f2bf(acc[i][j][2] + b4.z);
                pk.w = f2bf(acc[i][j][3] + b4.w);
                *(ushort4*)(dst + ((size_t)(bh * 2048 + s)) * 64 + j * 16 + q4) = pk;
            }
        }
    }

    // ---- fused mask-pack tail (per-wave, no barrier, no LDS):
    // bit j of mbitsT[b][kw][sq] = (mask[b][sq][kw*32+j] != 0); lane = kw.
    {
        int wid = gxr * 4 + w;  // [0, 3072)
        for (int row = wid; row < 4096; row += 3072) {
            const float* mrow = mask + (size_t)row * 2048 + lane * 32;
            unsigned int wbits = 0;
#pragma unroll
            for (int cc = 0; cc < 8; cc++) {
                float4 v = *(const float4*)(mrow + cc * 4);
                wbits |= (v.x != 0.0f ? 1u : 0u) << (cc * 4);
                wbits |= (v.y != 0.0f ? 2u : 0u) << (cc * 4);
                wbits |= (v.z != 0.0f ? 4u : 0u) << (cc * 4);
                wbits |= (v.w != 0.0f ? 8u : 0u) << (cc * 4);
            }
            int b = row >> 11, sq = row & 2047;
            mbitsT[((size_t)b * 64 + lane) * 2048 + sq] = wbits;
        }
    }
}

// ---------------------------------------------------------------- output GEMM
// Round-10: BK=64. LDS 24KB (A 128x64 + B 64x64), 2 blocks/CU unchanged;
// barrier events per block 64 -> 32. SWAPPED operands -> float4 epilogue.
__global__ __launch_bounds__(256) void out_gemm(
    const unsigned short* __restrict__ Amat,  // o_ws flat [4096][1024]
    const unsigned short* __restrict__ WoT,   // [1024][1024]
    const float* __restrict__ bo,
    float* __restrict__ out) {
    __shared__ unsigned short ldsA[8192], ldsB[4096];  // [128][64], [64][64]
    int gxr = blockIdx.x;
    int xcd = gxr & 7, lidx = gxr >> 3;            // lidx in [0,64)
    int m0 = (xcd * 4 + (lidx & 3)) * 128;         // m in [0,32)
    int n0 = (lidx >> 2) * 64;                     // n in [0,16)
    int tid = threadIdx.x;
    int w = tid >> 6, lane = tid & 63, quad = lane >> 4, l15 = lane & 15;
    int q4 = quad * 4;

    int r = tid >> 3, p = tid & 7;
    int c = (p - (r >> 1)) & 7;
    const unsigned short* gA = Amat + (size_t)(m0 + r) * 1024 + c * 8;
    const unsigned short* gB = WoT + (size_t)(n0 + r) * 1024 + c * 8;
    unsigned short* lA = ldsA + w * 512 + lane * 8;   // round i: + i*2048
    unsigned short* lB = ldsB + w * 512 + lane * 8;

    int wm = w >> 1, wn = w & 1;
    int posq = ((quad + (l15 >> 1)) & 7) * 8;
    int aoff = (wm * 64 + l15) * 64 + posq;
    int boff = (wn * 32 + l15) * 64 + posq;

    f32x4 acc[4][2] = {};
    for (int k0 = 0; k0 < 1024; k0 += 64) {
        __syncthreads();
#pragma unroll
        for (int i = 0; i < 4; i++)
            gld16(lA + i * 2048, gA + (size_t)i * 32 * 1024 + k0);
#pragma unroll
        for (int i = 0; i < 2; i++)
            gld16(lB + i * 2048, gB + (size_t)i * 32 * 1024 + k0);
        __syncthreads();
#pragma unroll
        for (int h = 0; h < 2; h++) {
            int ho = h * 32;
            bf16x8 af[4], bfr[2];
#pragma unroll
            for (int i = 0; i < 4; i++) af[i] = *(const bf16x8*)(ldsA + ((aoff + i * 1024) ^ ho));
#pragma unroll
            for (int j = 0; j < 2; j++) bfr[j] = *(const bf16x8*)(ldsB + ((boff + j * 1024) ^ ho));
            // swapped: acc rows = n (cols of C), cols = m (rows of C)
#pragma unroll
            for (int i = 0; i < 4; i++)
#pragma unroll
                for (int j = 0; j < 2; j++)
                    acc[i][j] = __builtin_amdgcn_mfma_f32_16x16x32_bf16(bfr[j], af[i], acc[i][j], 0, 0, 0);
        }
    }
    int ncol0 = n0 + wn * 32;
    int rBase = m0 + wm * 64;
#pragma unroll
    for (int j = 0; j < 2; j++) {
        float4 b4 = *(const float4*)(bo + ncol0 + j * 16 + q4);
#pragma unroll
        for (int i = 0; i < 4; i++) {
            int row = rBase + i * 16 + l15;
            float4 o4;
            o4.x = acc[i][j][0] + b4.x;
            o4.y = acc[i][j][1] + b4.y;
            o4.z = acc[i][j][2] + b4.z;
            o4.w = acc[i][j][3] + b4.w;
            *(float4*)(out + (size_t)row * 1024 + ncol0 + j * 16 + q4) = o4;
        }
    }
}

// ---------------------------------------------------------------- attention
// r7-validated body EXACTLY (measured 59.0-62.1 across r6/r7/r9; VGPR 52,
// conflicts 0). attn is at its issue/critical-path floor: dbuf (r1), Q2 (r2),
// 2x2-split (r4), coop-fusion (r8), counted-vmcnt (r9) all null/negative.
// Kept: 16-q/wave, 1024 blocks, dbuf w/ compile-time buffer offsets
// (kt-unroll x2), setprio on MFMA clusters, XCD chunking, Schraudolph M=16,
// ones-A l trick.
__global__ __launch_bounds__(256) void attn(
    const unsigned short* __restrict__ q_ws,   // [BH][S][HD]
    const unsigned short* __restrict__ k_ws,   // [BH][S][HD]
    const unsigned short* __restrict__ vB,     // [BH][32][2][4][64][8]
    const unsigned int* __restrict__ mbitsT,   // [B][64 kw][2048 q]
    unsigned short* __restrict__ o_ws) {       // [H][B][S][HD] flat
    __shared__ unsigned short ldsK[8192];  // [2][64 row][8 pos][8] ; pos = chunk ^ (row&7)
    __shared__ unsigned short ldsV[8192];  // [2] x kt tile of vB, natural order

    int tid = threadIdx.x;
    int w = tid >> 6, lane = tid & 63, quad = lane >> 4, l15 = lane & 15;
    int bxr = blockIdx.x;
    int bx = ((bxr & 7) << 7) | (bxr >> 3);  // XCD chunking (1024 = 8 x 128, bijective)
    int bh = bx >> 5, qt = bx & 31;
    int b = bh >> 4, h = bh & 15;

    int q = qt * 64 + w * 16 + l15;  // this lane's query (column n)
    const unsigned short* qptr = q_ws + ((size_t)(bh * 2048 + q)) * 64 + quad * 8;
    bf16x8 qf0 = *(const bf16x8*)(qptr);
    bf16x8 qf1 = *(const bf16x8*)(qptr + 32);

    const float c2 = 0.125f * 1.44269504089f;     // scale * log2(e)
    const float Cs = c2 * 8388608.0f;             // c2 * 2^23
    const float Ds = (127.0f - 16.0f) * 8388608.0f;  // constant bound M = 16

    const unsigned int* mb = mbitsT + (size_t)b * 64 * 2048 + q;
    const unsigned short* kbase = k_ws + (size_t)bh * 2048 * 64;
    const unsigned short* vbb = vB + (size_t)bh * 32 * 4096;

    // staging addresses (wave-uniform LDS base + lane*16)
    int srow = (lane >> 3);            // 0..7
    int spos = lane & 7;
    unsigned short* dK0 = ldsK + w * 1024 + lane * 8;  // buf0; buf1 = +4096
    unsigned short* dV0 = ldsV + w * 1024 + lane * 8;
    int r0 = w * 16 + srow;            // K rows this lane covers (first 8-row group)
    int r1 = r0 + 8;
    int g0 = spos ^ (r0 & 7);          // source chunk for swizzled LDS pos
    int g1 = spos ^ (r1 & 7);
    // prefetch source pointers, advanced += 4096 per staged tile
    const unsigned short* kS0n = kbase + (size_t)r0 * 64 + g0 * 8;
    const unsigned short* kS1n = kbase + (size_t)r1 * 64 + g1 * 8;
    const unsigned short* vSn  = vbb + (size_t)w * 1024 + lane * 8;
    const unsigned int* mbn = mb;      // mask words for next-staged tile

    f32x4 oacc[4] = {};  // O^T: hd = nb*16 + quad*4 + r (C-layout), col q = l15
    f32x4 lacc = {};     // l[q] in every reg (ones-A trick)
    bf16x8 onesA;
#pragma unroll
    for (int j = 0; j < 8; j++) onesA[j] = (short)0x3F80;

    int sw = (l15 & 7);
    int q4 = quad * 4;

    // prologue: stage tile 0 into buffer 0; preload mask words for kt=0
    gld16(dK0, kS0n);
    gld16(dK0 + 512, kS1n);
    gld16(dV0, vSn);
    gld16(dV0 + 512, vSn + 512);
    kS0n += 4096; kS1n += 4096; vSn += 4096;
    unsigned int mw0 = mbn[0];
    unsigned int mw1 = mbn[2048];
    mbn += 4096;
    __syncthreads();  // drains vmcnt -> tile 0 visible

    unsigned int nw0, nw1;

    // one kt sub-iteration; CO is a compile-time LDS short-offset (0 or 4096)
#define ATTN_BODY(KT, CO)                                                          \
    {                                                                              \
        nw0 = 0; nw1 = 0;                                                          \
        if ((KT) < 31) {  /* prefetch tile KT+1 into other buffer */               \
            gld16(dK0 + ((CO) ^ 4096), kS0n);                                      \
            gld16(dK0 + ((CO) ^ 4096) + 512, kS1n);                                \
            gld16(dV0 + ((CO) ^ 4096), vSn);                                       \
            gld16(dV0 + ((CO) ^ 4096) + 512, vSn + 512);                           \
            kS0n += 4096; kS1n += 4096; vSn += 4096;                               \
            nw0 = mbn[0]; nw1 = mbn[2048]; mbn += 4096;                            \
        }                                                                          \
        f32x4 sacc[4];                                                             \
        __builtin_amdgcn_s_setprio(1);                                             \
        _Pragma("unroll")                                                          \
        for (int nt = 0; nt < 4; nt++) {                                           \
            const unsigned short* kr = ldsK + (CO) + (nt * 16 + l15) * 64;         \
            bf16x8 kf0, kf1;                                                       \
            __builtin_memcpy(&kf0, kr + (quad ^ sw) * 8, 16);                      \
            __builtin_memcpy(&kf1, kr + ((quad + 4) ^ sw) * 8, 16);                \
            f32x4 z = {};                                                          \
            z = __builtin_amdgcn_mfma_f32_16x16x32_bf16(kf0, qf0, z, 0, 0, 0);     \
            z = __builtin_amdgcn_mfma_f32_16x16x32_bf16(kf1, qf1, z, 0, 0, 0);     \
            sacc[nt] = z;                                                          \
        }                                                                          \
        __builtin_amdgcn_s_setprio(0);                                             \
        unsigned int s0 = mw0 >> q4;                                               \
        unsigned int s1 = mw1 >> q4;                                               \
        unsigned int dw[4][2];                                                     \
        _Pragma("unroll")                                                          \
        for (int nt = 0; nt < 4; nt++) {                                           \
            unsigned int sel = (nt & 2) ? s1 : s0;                                 \
            unsigned int u[4];                                                     \
            _Pragma("unroll")                                                      \
            for (int rr = 0; rr < 4; rr++) {                                       \
                float y = __builtin_fmaf(sacc[nt][rr], Cs, Ds);                    \
                if ((sel >> ((nt & 1) * 16 + rr)) & 1u) y = 0.f;                   \
                u[rr] = (unsigned int)(int)y;                                      \
            }                                                                      \
            dw[nt][0] = __builtin_amdgcn_perm(u[1], u[0], 0x07060302u);            \
            dw[nt][1] = __builtin_amdgcn_perm(u[3], u[2], 0x07060302u);            \
        }                                                                          \
        __builtin_amdgcn_s_setprio(1);                                             \
        _Pragma("unroll")                                                          \
        for (int ks2 = 0; ks2 < 2; ks2++) {                                        \
            union { bf16x8 v; unsigned int d[4]; } bfr;                            \
            bfr.d[0] = dw[2 * ks2][0];                                             \
            bfr.d[1] = dw[2 * ks2][1];                                             \
            bfr.d[2] = dw[2 * ks2 + 1][0];                                         \
            bfr.d[3] = dw[2 * ks2 + 1][1];                                         \
            _Pragma("unroll")                                                      \
            for (int nb = 0; nb < 4; nb++) {                                       \
                bf16x8 vf;                                                         \
                __builtin_memcpy(&vf,                                              \
                    ldsV + (CO) + ((ks2 * 4 + quad) * 64 + nb * 16 + l15) * 8, 16);\
                oacc[nb] = __builtin_amdgcn_mfma_f32_16x16x32_bf16(vf, bfr.v,      \
                                                                   oacc[nb], 0, 0, 0); \
            }                                                                      \
            lacc = __builtin_amdgcn_mfma_f32_16x16x32_bf16(onesA, bfr.v, lacc,     \
                                                           0, 0, 0);               \
        }                                                                          \
        __builtin_amdgcn_s_setprio(0);                                             \
        __syncthreads();  /* drains prefetch vmcnt; buffer reusable */             \
        mw0 = nw0; mw1 = nw1;                                                      \
    }

    for (int kt = 0; kt < 32; kt += 2) {
        ATTN_BODY(kt, 0);
        ATTN_BODY(kt + 1, 4096);
    }
#undef ATTN_BODY

    // ---- normalize + store (every lane holds l[q] in all lacc regs)
    float linv = 1.0f / lacc[0];
    unsigned short* base = o_ws + ((size_t)((h * 2 + b) * 2048 + q)) * 64;
#pragma unroll
    for (int nb = 0; nb < 4; nb++) {
        ushort4 pk;
        pk.x = f2bf(oacc[nb][0] * linv);
        pk.y = f2bf(oacc[nb][1] * linv);
        pk.z = f2bf(oacc[nb][2] * linv);
        pk.w = f2bf(oacc[nb][3] * linv);
        *(ushort4*)(base + nb * 16 + quad * 4) = pk;
    }
}

// ---------------------------------------------------------------- launch

extern "C" void kernel_launch(void* const* d_in, const int* in_sizes, int n_in,
                              void* d_out, int out_size, void* d_ws, size_t ws_size,
                              hipStream_t stream) {
    const float* x    = (const float*)d_in[0];
    const float* mask = (const float*)d_in[1];
    const float* Wqkv = (const float*)d_in[2];
    const float* bqkv = (const float*)d_in[3];
    const float* Wo   = (const float*)d_in[4];
    const float* bo   = (const float*)d_in[5];
    float* out = (float*)d_out;

    char* ws = (char*)d_ws;
    unsigned short* xb    = (unsigned short*)(ws);                       // 8 MB
    unsigned short* WqkvT = (unsigned short*)(ws + ((size_t)8 << 20));   // 6 MB
    unsigned short* WoT   = (unsigned short*)(ws + ((size_t)14 << 20));  // 2 MB
    unsigned short* q_ws  = (unsigned short*)(ws + ((size_t)16 << 20));  // 8 MB
    unsigned short* k_ws  = (unsigned short*)(ws + ((size_t)24 << 20));  // 8 MB
    unsigned short* vB    = (unsigned short*)(ws + ((size_t)32 << 20));  // 8 MB
    unsigned short* o_ws  = (unsigned short*)(ws + ((size_t)40 << 20));  // 8 MB
    unsigned int*   mbits = (unsigned int*)(ws + ((size_t)48 << 20));    // 1 MB

    prep<<<8192, 256, 0, stream>>>(x, xb, Wqkv, WqkvT, Wo, WoT);
    qkv_gemm<<<768, 256, 0, stream>>>(xb, WqkvT, bqkv, mask, mbits, q_ws, k_ws, vB);
    attn<<<1024, 256, 0, stream>>>(q_ws, k_ws, vB, mbits, o_ws);
    out_gemm<<<512, 256, 0, stream>>>(o_ws, WoT, bo, out);
}

// Round 11
// 219.676 us; speedup vs baseline: 1.0796x; 1.0796x over previous
//
#include <hip/hip_runtime.h>
#include <stdint.h>

// Problem constants: B=2, S=2048, D=1024, H=16, HD=64
#define BB 2
#define SS 2048
#define DD 1024
#define HH 16
#define HD 64
#define BH 32    // B*H
#define BS 4096  // B*S

typedef short bf16x8 __attribute__((ext_vector_type(8)));
typedef float f32x4 __attribute__((ext_vector_type(4)));

static __device__ __forceinline__ unsigned short f2bf(float f) {
    union { float f; unsigned int u; } x;
    x.f = f;
    unsigned int u = x.u;
    unsigned int r = u + 0x7FFFu + ((u >> 16) & 1u);  // round-to-nearest-even
    return (unsigned short)(r >> 16);
}

// async global->LDS, 16B per lane; LDS dst is wave-uniform base + lane*16
static __device__ __forceinline__ void gld16(unsigned short* lds, const unsigned short* g) {
    __builtin_amdgcn_global_load_lds(
        (const __attribute__((address_space(1))) unsigned int*)g,
        (__attribute__((address_space(3))) unsigned int*)lds,
        16, 0, 0);
}

// ---------------------------------------------------------------- fused prep
// blocks [0,4096)     : x f32 -> bf16
// blocks [4096,7168)  : transpose Wqkv -> WqkvT bf16
// blocks [7168,8192)  : transpose Wo   -> WoT   bf16
// (mask-pack lives in qkv_gemm's per-wave tail: its 32MB read overlaps MFMA)
__global__ __launch_bounds__(256) void prep(
    const float* __restrict__ x, unsigned short* __restrict__ xb,
    const float* __restrict__ Wqkv, unsigned short* __restrict__ WqkvT,
    const float* __restrict__ Wo, unsigned short* __restrict__ WoT) {
    __shared__ float tile[32][33];
    int bid = blockIdx.x;
    int tid = threadIdx.x;
    if (bid < 4096) {
        int i = (bid * 256 + tid) * 4;
        float4 v = *(const float4*)(x + i);
        ushort4 o;
        o.x = f2bf(v.x); o.y = f2bf(v.y); o.z = f2bf(v.z); o.w = f2bf(v.w);
        *(ushort4*)(xb + i) = o;
    } else {
        const float* W;
        unsigned short* WT;
        int N, t;
        if (bid < 7168) { W = Wqkv; WT = WqkvT; N = 3072; t = bid - 4096; }
        else            { W = Wo;   WT = WoT;   N = 1024; t = bid - 7168; }
        const int K = 1024;
        int nx = N >> 5;
        int n0 = (t % nx) * 32, k0 = (t / nx) * 32;
        int tx = tid & 31, ty = tid >> 5;  // 32 x 8
#pragma unroll
        for (int i = 0; i < 4; i++)
            tile[ty + i * 8][tx] = W[(size_t)(k0 + ty + i * 8) * N + n0 + tx];
        __syncthreads();
#pragma unroll
        for (int i = 0; i < 4; i++)
            WT[(size_t)(n0 + ty + i * 8) * K + k0 + tx] = f2bf(tile[tx][ty + i * 8]);
    }
}

// ---------------------------------------------------------------- QKV GEMM
// 128x128 tile, BK=32, single-buffer 2-barrier loop; XCD-bijective swizzle
// (m-fastest chunks). q/k blocks use SWAPPED MFMA operands -> C^T in acc ->
// vectorized ushort4 epilogue. Per-wave mask-pack tail overlaps sibling MFMA.
// (r10's BK=64 variant measured WORSE: 73us, 3.1M bank conflicts, VGPR 132,
//  occupancy 10% -- the mod-8 swizzle at row-stride-128B is phase-imbalanced.)
// vB : [BH][32 kt][2 ks2][4 quad][64 hd][8 j] with
// key(ks2,quad,j) = ks2*32 + (j>>2)*16 + quad*4 + (j&3)   (matches attn)
__global__ __launch_bounds__(256) void qkv_gemm(
    const unsigned short* __restrict__ xb,     // [4096][1024]
    const unsigned short* __restrict__ WqkvT,  // [3072][1024]
    const float* __restrict__ bqkv,            // [3072]
    const float* __restrict__ mask,            // [B][S][S]
    unsigned int* __restrict__ mbitsT,         // [B][64 kw][2048 q]
    unsigned short* __restrict__ q_ws,
    unsigned short* __restrict__ k_ws,
    unsigned short* __restrict__ vB) {
    __shared__ unsigned short ldsA[4096], ldsB[4096];
    int gxr = blockIdx.x;
    int tid = threadIdx.x;
    int xcd = gxr & 7, lidx = gxr >> 3;            // lidx in [0,96)
    int m0 = (xcd * 4 + (lidx & 3)) * 128;         // m in [0,32)
    int n0 = (lidx >> 2) * 128;                    // n in [0,24)
    int w = tid >> 6, lane = tid & 63, quad = lane >> 4, l15 = lane & 15;
    int q4 = quad * 4;

    int r = tid >> 2, p = tid & 3;
    int c = (p - (r >> 1)) & 3;  // chunk swizzle: LDS pos p of row r holds chunk (p+(r>>1))&3
    const unsigned short* gA0 = xb + (size_t)(m0 + r) * 1024 + c * 8;
    const unsigned short* gA1 = gA0 + (size_t)64 * 1024;
    const unsigned short* gB0 = WqkvT + (size_t)(n0 + r) * 1024 + c * 8;
    const unsigned short* gB1 = gB0 + (size_t)64 * 1024;
    unsigned short* lA0 = ldsA + w * 512;
    unsigned short* lA1 = ldsA + 2048 + w * 512;
    unsigned short* lB0 = ldsB + w * 512;
    unsigned short* lB1 = ldsB + 2048 + w * 512;

    int wm = w >> 1, wn = w & 1;
    int posq = ((quad + (l15 >> 1)) & 3) * 8;
    int aoff = (wm * 64 + l15) * 32 + posq;
    int boff = (wn * 64 + l15) * 32 + posq;

    int t = n0 >> 10;
    f32x4 acc[4][4] = {};
    if (t == 2) {
        for (int k0 = 0; k0 < 1024; k0 += 32) {
            __syncthreads();
            gld16(lA0, gA0 + k0);
            gld16(lA1, gA1 + k0);
            gld16(lB0, gB0 + k0);
            gld16(lB1, gB1 + k0);
            __syncthreads();
            bf16x8 af[4], bfr[4];
#pragma unroll
            for (int i = 0; i < 4; i++) {
                af[i]  = *(const bf16x8*)(ldsA + aoff + i * 512);
                bfr[i] = *(const bf16x8*)(ldsB + boff + i * 512);
            }
#pragma unroll
            for (int i = 0; i < 4; i++)
#pragma unroll
                for (int j = 0; j < 4; j++)
                    acc[i][j] = __builtin_amdgcn_mfma_f32_16x16x32_bf16(af[i], bfr[j], acc[i][j], 0, 0, 0);
        }
    } else {
        for (int k0 = 0; k0 < 1024; k0 += 32) {
            __syncthreads();
            gld16(lA0, gA0 + k0);
            gld16(lA1, gA1 + k0);
            gld16(lB0, gB0 + k0);
            gld16(lB1, gB1 + k0);
            __syncthreads();
            bf16x8 af[4], bfr[4];
#pragma unroll
            for (int i = 0; i < 4; i++) {
                af[i]  = *(const bf16x8*)(ldsA + aoff + i * 512);
                bfr[i] = *(const bf16x8*)(ldsB + boff + i * 512);
            }
            // swapped operands -> acc holds C^T (rows = hd, cols = s)
#pragma unroll
            for (int i = 0; i < 4; i++)
#pragma unroll
                for (int j = 0; j < 4; j++)
                    acc[i][j] = __builtin_amdgcn_mfma_f32_16x16x32_bf16(bfr[j], af[i], acc[i][j], 0, 0, 0);
        }
    }

    int ncol0 = n0 + wn * 64;
    int hh = (ncol0 >> 6) & 15;

    if (t == 2) {
        int rowbase = m0 + wm * 64;            // wave-uniform, multiple of 64
        int b = rowbase >> 11;
        int kt = (rowbase >> 6) & 31;
        int bh = b * 16 + hh;
#pragma unroll
        for (int j = 0; j < 4; j++) {
            int hd = j * 16 + l15;
            float bias = bqkv[ncol0 + hd];
#pragma unroll
            for (int i = 0; i < 4; i++) {
                unsigned short* dst = vB +
                    (((((size_t)bh * 32 + kt) * 2 + (i >> 1)) * 4 + quad) * 64 + hd) * 8 + (i & 1) * 4;
                ushort4 pk;
                pk.x = f2bf(acc[i][j][0] + bias);
                pk.y = f2bf(acc[i][j][1] + bias);
                pk.z = f2bf(acc[i][j][2] + bias);
                pk.w = f2bf(acc[i][j][3] + bias);
                *(ushort4*)dst = pk;
            }
        }
    } else {
        // swapped epilogue: thread holds cols n = ncol0 + j*16 + q4 + rr at
        // fixed row s = m0 + wm*64 + i*16 + l15 -> one ushort4 per (i,j)
        unsigned short* dst = (t == 0) ? q_ws : k_ws;
        int sBase = m0 + wm * 64;
#pragma unroll
        for (int j = 0; j < 4; j++) {
            float4 b4 = *(const float4*)(bqkv + ncol0 + j * 16 + q4);
#pragma unroll
            for (int i = 0; i < 4; i++) {
                int row = sBase + i * 16 + l15;
                int b = row >> 11, s = row & 2047;
                int bh = b * 16 + hh;
                ushort4 pk;
                pk.x = f2bf(acc[i][j][0] + b4.x);
                pk.y = f2bf(acc[i][j][1] + b4.y);
                pk.z = f2bf(acc[i][j][2] + b4.z);
                pk.w = f2bf(acc[i][j][3] + b4.w);
                *(ushort4*)(dst + ((size_t)(bh * 2048 + s)) * 64 + j * 16 + q4) = pk;
            }
        }
    }

    // ---- fused mask-pack tail (per-wave, no barrier, no LDS):
    // bit j of mbitsT[b][kw][sq] = (mask[b][sq][kw*32+j] != 0); lane = kw.
    {
        int wid = gxr * 4 + w;  // [0, 3072)
        for (int row = wid; row < 4096; row += 3072) {
            const float* mrow = mask + (size_t)row * 2048 + lane * 32;
            unsigned int wbits = 0;
#pragma unroll
            for (int cc = 0; cc < 8; cc++) {
                float4 v = *(const float4*)(mrow + cc * 4);
                wbits |= (v.x != 0.0f ? 1u : 0u) << (cc * 4);
                wbits |= (v.y != 0.0f ? 2u : 0u) << (cc * 4);
                wbits |= (v.z != 0.0f ? 4u : 0u) << (cc * 4);
                wbits |= (v.w != 0.0f ? 8u : 0u) << (cc * 4);
            }
            int b = row >> 11, sq = row & 2047;
            mbitsT[((size_t)b * 64 + lane) * 2048 + sq] = wbits;
        }
    }
}

// ---------------------------------------------------------------- output GEMM
// 128x64 tile -> 512 blocks (2 blocks/CU), 4 waves 2m x 2n, wave = 64x32.
// XCD-bijective swizzle, m-fastest. SWAPPED operands -> float4 epilogue.
__global__ __launch_bounds__(256) void out_gemm(
    const unsigned short* __restrict__ Amat,  // o_ws flat [4096][1024]
    const unsigned short* __restrict__ WoT,   // [1024][1024]
    const float* __restrict__ bo,
    float* __restrict__ out) {
    __shared__ unsigned short ldsA[4096], ldsB[2048];
    int gxr = blockIdx.x;
    int xcd = gxr & 7, lidx = gxr >> 3;            // lidx in [0,64)
    int m0 = (xcd * 4 + (lidx & 3)) * 128;         // m in [0,32)
    int n0 = (lidx >> 2) * 64;                     // n in [0,16)
    int tid = threadIdx.x;
    int w = tid >> 6, lane = tid & 63, quad = lane >> 4, l15 = lane & 15;
    int q4 = quad * 4;

    int r = tid >> 2, p = tid & 3;
    int c = (p - (r >> 1)) & 3;
    const unsigned short* gA0 = Amat + (size_t)(m0 + r) * 1024 + c * 8;
    const unsigned short* gA1 = gA0 + (size_t)64 * 1024;
    const unsigned short* gB0 = WoT + (size_t)(n0 + r) * 1024 + c * 8;
    unsigned short* lA0 = ldsA + w * 512;
    unsigned short* lA1 = ldsA + 2048 + w * 512;
    unsigned short* lB0 = ldsB + w * 512;

    int wm = w >> 1, wn = w & 1;
    int posq = ((quad + (l15 >> 1)) & 3) * 8;
    int aoff = (wm * 64 + l15) * 32 + posq;
    int boff = (wn * 32 + l15) * 32 + posq;

    f32x4 acc[4][2] = {};
    for (int k0 = 0; k0 < 1024; k0 += 32) {
        __syncthreads();
        gld16(lA0, gA0 + k0);
        gld16(lA1, gA1 + k0);
        gld16(lB0, gB0 + k0);
        __syncthreads();
        bf16x8 af[4], bfr[2];
#pragma unroll
        for (int i = 0; i < 4; i++) af[i] = *(const bf16x8*)(ldsA + aoff + i * 512);
#pragma unroll
        for (int j = 0; j < 2; j++) bfr[j] = *(const bf16x8*)(ldsB + boff + j * 512);
        // swapped: acc rows = n (cols of C), cols = m (rows of C)
#pragma unroll
        for (int i = 0; i < 4; i++)
#pragma unroll
            for (int j = 0; j < 2; j++)
                acc[i][j] = __builtin_amdgcn_mfma_f32_16x16x32_bf16(bfr[j], af[i], acc[i][j], 0, 0, 0);
    }
    int ncol0 = n0 + wn * 32;
    int rBase = m0 + wm * 64;
#pragma unroll
    for (int j = 0; j < 2; j++) {
        float4 b4 = *(const float4*)(bo + ncol0 + j * 16 + q4);
#pragma unroll
        for (int i = 0; i < 4; i++) {
            int row = rBase + i * 16 + l15;
            float4 o4;
            o4.x = acc[i][j][0] + b4.x;
            o4.y = acc[i][j][1] + b4.y;
            o4.z = acc[i][j][2] + b4.z;
            o4.w = acc[i][j][3] + b4.w;
            *(float4*)(out + (size_t)row * 1024 + ncol0 + j * 16 + q4) = o4;
        }
    }
}

// ---------------------------------------------------------------- attention
// r3/r6/r7-validated body EXACTLY (measured 59.0-62.1; VGPR 52, conflicts 0).
// attn is at its issue/critical-path floor: dbuf (r1), Q2 (r2), 2x2-split
// (r4), coop-fusion (r8), counted-vmcnt (r9) all null/negative. Kept:
// 16-q/wave, 1024 blocks, dbuf w/ compile-time buffer offsets (kt-unroll x2),
// setprio on MFMA clusters, XCD chunking, Schraudolph M=16, ones-A l trick.
__global__ __launch_bounds__(256) void attn(
    const unsigned short* __restrict__ q_ws,   // [BH][S][HD]
    const unsigned short* __restrict__ k_ws,   // [BH][S][HD]
    const unsigned short* __restrict__ vB,     // [BH][32][2][4][64][8]
    const unsigned int* __restrict__ mbitsT,   // [B][64 kw][2048 q]
    unsigned short* __restrict__ o_ws) {       // [H][B][S][HD] flat
    __shared__ unsigned short ldsK[8192];  // [2][64 row][8 pos][8] ; pos = chunk ^ (row&7)
    __shared__ unsigned short ldsV[8192];  // [2] x kt tile of vB, natural order

    int tid = threadIdx.x;
    int w = tid >> 6, lane = tid & 63, quad = lane >> 4, l15 = lane & 15;
    int bxr = blockIdx.x;
    int bx = ((bxr & 7) << 7) | (bxr >> 3);  // XCD chunking (1024 = 8 x 128, bijective)
    int bh = bx >> 5, qt = bx & 31;
    int b = bh >> 4, h = bh & 15;

    int q = qt * 64 + w * 16 + l15;  // this lane's query (column n)
    const unsigned short* qptr = q_ws + ((size_t)(bh * 2048 + q)) * 64 + quad * 8;
    bf16x8 qf0 = *(const bf16x8*)(qptr);
    bf16x8 qf1 = *(const bf16x8*)(qptr + 32);

    const float c2 = 0.125f * 1.44269504089f;     // scale * log2(e)
    const float Cs = c2 * 8388608.0f;             // c2 * 2^23
    const float Ds = (127.0f - 16.0f) * 8388608.0f;  // constant bound M = 16

    const unsigned int* mb = mbitsT + (size_t)b * 64 * 2048 + q;
    const unsigned short* kbase = k_ws + (size_t)bh * 2048 * 64;
    const unsigned short* vbb = vB + (size_t)bh * 32 * 4096;

    // staging addresses (wave-uniform LDS base + lane*16)
    int srow = (lane >> 3);            // 0..7
    int spos = lane & 7;
    unsigned short* dK0 = ldsK + w * 1024 + lane * 8;  // buf0; buf1 = +4096
    unsigned short* dV0 = ldsV + w * 1024 + lane * 8;
    int r0 = w * 16 + srow;            // K rows this lane covers (first 8-row group)
    int r1 = r0 + 8;
    int g0 = spos ^ (r0 & 7);          // source chunk for swizzled LDS pos
    int g1 = spos ^ (r1 & 7);
    // prefetch source pointers, advanced += 4096 per staged tile
    const unsigned short* kS0n = kbase + (size_t)r0 * 64 + g0 * 8;
    const unsigned short* kS1n = kbase + (size_t)r1 * 64 + g1 * 8;
    const unsigned short* vSn  = vbb + (size_t)w * 1024 + lane * 8;
    const unsigned int* mbn = mb;      // mask words for next-staged tile

    f32x4 oacc[4] = {};  // O^T: hd = nb*16 + quad*4 + r (C-layout), col q = l15
    f32x4 lacc = {};     // l[q] in every reg (ones-A trick)
    bf16x8 onesA;
#pragma unroll
    for (int j = 0; j < 8; j++) onesA[j] = (short)0x3F80;

    int sw = (l15 & 7);
    int q4 = quad * 4;

    // prologue: stage tile 0 into buffer 0; preload mask words for kt=0
    gld16(dK0, kS0n);
    gld16(dK0 + 512, kS1n);
    gld16(dV0, vSn);
    gld16(dV0 + 512, vSn + 512);
    kS0n += 4096; kS1n += 4096; vSn += 4096;
    unsigned int mw0 = mbn[0];
    unsigned int mw1 = mbn[2048];
    mbn += 4096;
    __syncthreads();  // drains vmcnt -> tile 0 visible

    unsigned int nw0, nw1;

    // one kt sub-iteration; CO is a compile-time LDS short-offset (0 or 4096)
#define ATTN_BODY(KT, CO)                                                          \
    {                                                                              \
        nw0 = 0; nw1 = 0;                                                          \
        if ((KT) < 31) {  /* prefetch tile KT+1 into other buffer */               \
            gld16(dK0 + ((CO) ^ 4096), kS0n);                                      \
            gld16(dK0 + ((CO) ^ 4096) + 512, kS1n);                                \
            gld16(dV0 + ((CO) ^ 4096), vSn);                                       \
            gld16(dV0 + ((CO) ^ 4096) + 512, vSn + 512);                           \
            kS0n += 4096; kS1n += 4096; vSn += 4096;                               \
            nw0 = mbn[0]; nw1 = mbn[2048]; mbn += 4096;                            \
        }                                                                          \
        f32x4 sacc[4];                                                             \
        __builtin_amdgcn_s_setprio(1);                                             \
        _Pragma("unroll")                                                          \
        for (int nt = 0; nt < 4; nt++) {                                           \
            const unsigned short* kr = ldsK + (CO) + (nt * 16 + l15) * 64;         \
            bf16x8 kf0, kf1;                                                       \
            __builtin_memcpy(&kf0, kr + (quad ^ sw) * 8, 16);                      \
            __builtin_memcpy(&kf1, kr + ((quad + 4) ^ sw) * 8, 16);                \
            f32x4 z = {};                                                          \
            z = __builtin_amdgcn_mfma_f32_16x16x32_bf16(kf0, qf0, z, 0, 0, 0);     \
            z = __builtin_amdgcn_mfma_f32_16x16x32_bf16(kf1, qf1, z, 0, 0, 0);     \
            sacc[nt] = z;                                                          \
        }                                                                          \
        __builtin_amdgcn_s_setprio(0);                                             \
        unsigned int s0 = mw0 >> q4;                                               \
        unsigned int s1 = mw1 >> q4;                                               \
        unsigned int dw[4][2];                                                     \
        _Pragma("unroll")                                                          \
        for (int nt = 0; nt < 4; nt++) {                                           \
            unsigned int sel = (nt & 2) ? s1 : s0;                                 \
            unsigned int u[4];                                                     \
            _Pragma("unroll")                                                      \
            for (int rr = 0; rr < 4; rr++) {                                       \
                float y = __builtin_fmaf(sacc[nt][rr], Cs, Ds);                    \
                if ((sel >> ((nt & 1) * 16 + rr)) & 1u) y = 0.f;                   \
                u[rr] = (unsigned int)(int)y;                                      \
            }                                                                      \
            dw[nt][0] = __builtin_amdgcn_perm(u[1], u[0], 0x07060302u);            \
            dw[nt][1] = __builtin_amdgcn_perm(u[3], u[2], 0x07060302u);            \
        }                                                                          \
        __builtin_amdgcn_s_setprio(1);                                             \
        _Pragma("unroll")                                                          \
        for (int ks2 = 0; ks2 < 2; ks2++) {                                        \
            union { bf16x8 v; unsigned int d[4]; } bfr;                            \
            bfr.d[0] = dw[2 * ks2][0];                                             \
            bfr.d[1] = dw[2 * ks2][1];                                             \
            bfr.d[2] = dw[2 * ks2 + 1][0];                                         \
            bfr.d[3] = dw[2 * ks2 + 1][1];                                         \
            _Pragma("unroll")                                                      \
            for (int nb = 0; nb < 4; nb++) {                                       \
                bf16x8 vf;                                                         \
                __builtin_memcpy(&vf,                                              \
                    ldsV + (CO) + ((ks2 * 4 + quad) * 64 + nb * 16 + l15) * 8, 16);\
                oacc[nb] = __builtin_amdgcn_mfma_f32_16x16x32_bf16(vf, bfr.v,      \
                                                                   oacc[nb], 0, 0, 0); \
            }                                                                      \
            lacc = __builtin_amdgcn_mfma_f32_16x16x32_bf16(onesA, bfr.v, lacc,     \
                                                           0, 0, 0);               \
        }                                                                          \
        __builtin_amdgcn_s_setprio(0);                                             \
        __syncthreads();  /* drains prefetch vmcnt; buffer reusable */             \
        mw0 = nw0; mw1 = nw1;                                                      \
    }

    for (int kt = 0; kt < 32; kt += 2) {
        ATTN_BODY(kt, 0);
        ATTN_BODY(kt + 1, 4096);
    }
#undef ATTN_BODY

    // ---- normalize + store (every lane holds l[q] in all lacc regs)
    float linv = 1.0f / lacc[0];
    unsigned short* base = o_ws + ((size_t)((h * 2 + b) * 2048 + q)) * 64;
#pragma unroll
    for (int nb = 0; nb < 4; nb++) {
        ushort4 pk;
        pk.x = f2bf(oacc[nb][0] * linv);
        pk.y = f2bf(oacc[nb][1] * linv);
        pk.z = f2bf(oacc[nb][2] * linv);
        pk.w = f2bf(oacc[nb][3] * linv);
        *(ushort4*)(base + nb * 16 + quad * 4) = pk;
    }
}

// ---------------------------------------------------------------- launch

extern "C" void kernel_launch(void* const* d_in, const int* in_sizes, int n_in,
                              void* d_out, int out_size, void* d_ws, size_t ws_size,
                              hipStream_t stream) {
    const float* x    = (const float*)d_in[0];
    const float* mask = (const float*)d_in[1];
    const float* Wqkv = (const float*)d_in[2];
    const float* bqkv = (const float*)d_in[3];
    const float* Wo   = (const float*)d_in[4];
    const float* bo   = (const float*)d_in[5];
    float* out = (float*)d_out;

    char* ws = (char*)d_ws;
    unsigned short* xb    = (unsigned short*)(ws);                       // 8 MB
    unsigned short* WqkvT = (unsigned short*)(ws + ((size_t)8 << 20));   // 6 MB
    unsigned short* WoT   = (unsigned short*)(ws + ((size_t)14 << 20));  // 2 MB
    unsigned short* q_ws  = (unsigned short*)(ws + ((size_t)16 << 20));  // 8 MB
    unsigned short* k_ws  = (unsigned short*)(ws + ((size_t)24 << 20));  // 8 MB
    unsigned short* vB    = (unsigned short*)(ws + ((size_t)32 << 20));  // 8 MB
    unsigned short* o_ws  = (unsigned short*)(ws + ((size_t)40 << 20));  // 8 MB
    unsigned int*   mbits = (unsigned int*)(ws + ((size_t)48 << 20));    // 1 MB

    prep<<<8192, 256, 0, stream>>>(x, xb, Wqkv, WqkvT, Wo, WoT);
    qkv_gemm<<<768, 256, 0, stream>>>(xb, WqkvT, bqkv, mask, mbits, q_ws, k_ws, vB);
    attn<<<1024, 256, 0, stream>>>(q_ws, k_ws, vB, mbits, o_ws);
    out_gemm<<<512, 256, 0, stream>>>(o_ws, WoT, bo, out);
}